// Round 1
// baseline (333.214 us; speedup 1.0000x reference)
//
#include <hip/hip_runtime.h>
#include <math.h>

#define BB   16
#define RR   4096
#define CCLS 81
#define NC   80          // C-1 foreground classes
#define KK   300
#define DD   100
#define FLAT (NC * KK)   // 24000

__device__ __forceinline__ unsigned flip32(unsigned u) {
    // order-preserving map float bits -> unsigned (handles negatives, e.g. -1.0 sentinels)
    return (u & 0x80000000u) ? ~u : (u | 0x80000000u);
}
__device__ __forceinline__ unsigned unflip32(unsigned u) {
    return (u & 0x80000000u) ? (u ^ 0x80000000u) : ~u;
}

// ---------------- Kernel A: softmax + transpose to [B][80][R] ----------------
__global__ __launch_bounds__(256) void softmax_t_kernel(
        const float* __restrict__ logits, float* __restrict__ probs_t) {
    __shared__ float tile[64 * 81];
    __shared__ float srow_s[64];
    const int tid  = threadIdx.x;
    const int row0 = blockIdx.x * 64;            // global proposal row (64 rows/WG, same image)

    for (int idx = tid; idx < 64 * 81; idx += 256)
        tile[idx] = logits[(size_t)row0 * 81 + idx];
    __syncthreads();

    if (tid < 64) {
        float* rowp = &tile[tid * 81];
        float m = -1e30f;
        for (int c = 0; c < 81; ++c) m = fmaxf(m, rowp[c]);
        float s = 0.0f;
        for (int c = 0; c < 81; ++c) { float e = expf(rowp[c] - m); rowp[c] = e; s += e; }
        srow_s[tid] = s;
    }
    __syncthreads();

    const int b     = row0 >> 12;     // /4096
    const int rbase = row0 & 4095;
    for (int idx = tid; idx < 64 * 80; idx += 256) {
        int c1 = idx >> 6;            // 0..79  (class-1)
        int r  = idx & 63;
        float v = tile[r * 81 + (c1 + 1)] / srow_s[r];
        probs_t[((size_t)(b * 80 + c1)) * 4096 + rbase + r] = v;
    }
}

// ------------- Kernel B: per (image,class) top-K + decode + NMS --------------
__global__ __launch_bounds__(256) void percls_kernel(
        const float* __restrict__ probs_t,
        const float* __restrict__ box_reg,
        const float* __restrict__ proposals,
        float*       __restrict__ flat_s,
        float4*      __restrict__ flat_b) {
    #pragma clang fp contract(off)
    __shared__ unsigned long long keys[512];
    __shared__ float bx1[KK], by1[KK], bx2[KK], by2[KK], barea[KK];
    __shared__ int   keep[KK];
    __shared__ int   cnt;

    const int bid = blockIdx.x;       // 0..1279
    const int b   = bid / 80;
    const int ci  = bid % 80;         // class-1
    const int tid = threadIdx.x;

    if (tid == 0) cnt = 0;
    __syncthreads();

    // 1) compact indices with score > 0.05 (scores are positive -> raw bits sortable)
    const float* sp = probs_t + (size_t)bid * 4096;
    for (int r = tid; r < 4096; r += 256) {
        float s = sp[r];
        if (s > 0.05f) {
            int pos = atomicAdd(&cnt, 1);
            if (pos < 512)
                keys[pos] = ((unsigned long long)__float_as_uint(s) << 32)
                          | (unsigned)(~(unsigned)r);   // smaller r wins ties in desc sort
        }
    }
    __syncthreads();
    int M = cnt; if (M > 512) M = 512;
    for (int i = tid; i < 512; i += 256) if (i >= M) keys[i] = 0ULL;
    __syncthreads();

    // 2) bitonic sort 512, descending
    for (int k = 2; k <= 512; k <<= 1) {
        for (int j = k >> 1; j > 0; j >>= 1) {
            for (int i = tid; i < 512; i += 256) {
                int ixj = i ^ j;
                if (ixj > i) {
                    bool desc = ((i & k) == 0);
                    unsigned long long a = keys[i], c = keys[ixj];
                    if (desc ? (a < c) : (a > c)) { keys[i] = c; keys[ixj] = a; }
                }
            }
            __syncthreads();
        }
    }

    const int N = (M < KK) ? M : KK;

    // 3) decode + clip selected boxes (exactly reference op order; no FMA contraction)
    for (int k2 = tid; k2 < N; k2 += 256) {
        unsigned long long key = keys[k2];
        unsigned r = ~(unsigned)(key & 0xFFFFFFFFu);
        size_t n = (size_t)b * 4096 + r;
        float px1 = proposals[n * 4 + 0], py1 = proposals[n * 4 + 1];
        float px2 = proposals[n * 4 + 2], py2 = proposals[n * 4 + 3];
        const float* rg = box_reg + n * 324 + (size_t)(ci + 1) * 4;
        float dx = rg[0] / 10.0f;
        float dy = rg[1] / 10.0f;
        float dw = fminf(rg[2] / 5.0f, 4.135166556742356f);
        float dh = fminf(rg[3] / 5.0f, 4.135166556742356f);
        float w  = px2 - px1 + 1.0f;
        float h  = py2 - py1 + 1.0f;
        float cx = px1 + 0.5f * w;
        float cy = py1 + 0.5f * h;
        float pcx = dx * w + cx;
        float pcy = dy * h + cy;
        float pw  = expf(dw) * w;
        float ph  = expf(dh) * h;
        float x1 = pcx - 0.5f * pw;
        float y1 = pcy - 0.5f * ph;
        float x2 = pcx + 0.5f * pw - 1.0f;
        float y2 = pcy + 0.5f * ph - 1.0f;
        x1 = fminf(fmaxf(x1, 0.0f), 1332.0f);
        y1 = fminf(fmaxf(y1, 0.0f), 799.0f);
        x2 = fminf(fmaxf(x2, 0.0f), 1332.0f);
        y2 = fminf(fmaxf(y2, 0.0f), 799.0f);
        bx1[k2] = x1; by1[k2] = y1; bx2[k2] = x2; by2[k2] = y2;
        barea[k2] = (x2 - x1 + 1.0f) * (y2 - y1 + 1.0f);
        keep[k2]  = 1;
    }
    __syncthreads();

    // 4) greedy NMS (reference fori_loop equivalent; all entries here are valid)
    for (int i = 0; i < N; ++i) {
        __syncthreads();
        if (!keep[i]) continue;       // uniform (LDS broadcast)
        float ax1 = bx1[i], ay1 = by1[i], ax2 = bx2[i], ay2 = by2[i], aar = barea[i];
        for (int j2 = i + 1 + tid; j2 < N; j2 += 256) {
            if (!keep[j2]) continue;
            float ltx = fmaxf(ax1, bx1[j2]);
            float lty = fmaxf(ay1, by1[j2]);
            float rbx = fminf(ax2, bx2[j2]);
            float rby = fminf(ay2, by2[j2]);
            float iw  = fmaxf(rbx - ltx + 1.0f, 0.0f);
            float ih  = fmaxf(rby - lty + 1.0f, 0.0f);
            float inter = iw * ih;
            float iou   = inter / ((aar + barea[j2]) - inter);
            if (iou > 0.5f) keep[j2] = 0;
        }
    }
    __syncthreads();

    // 5) emit per-class slots
    const int base = b * FLAT + ci * KK;
    for (int k2 = tid; k2 < KK; k2 += 256) {
        float s; float4 bb;
        if (k2 < N) {
            s  = keep[k2] ? __uint_as_float((unsigned)(keys[k2] >> 32)) : -1.0f;
            bb = make_float4(bx1[k2], by1[k2], bx2[k2], by2[k2]);
        } else {
            s  = -1.0f;
            bb = make_float4(0.0f, 0.0f, 0.0f, 0.0f);
        }
        flat_s[base + k2] = s;
        flat_b[base + k2] = bb;
    }
}

// --------------- Kernel C: per-image exact top-100 + output ------------------
__global__ __launch_bounds__(256) void topd_kernel(
        const float*  __restrict__ flat_s,
        const float4* __restrict__ flat_b,
        float*        __restrict__ out) {
    __shared__ unsigned hist[256];
    __shared__ unsigned long long cand[512];
    __shared__ int sh_bin, sh_trem, sh_cnt;

    const int b   = blockIdx.x;
    const int tid = threadIdx.x;
    const float* sp = flat_s + (size_t)b * FLAT;

    // radix-select the 100th-largest sortable key (4 x 8-bit passes)
    unsigned prefix = 0, mask = 0;
    int t = DD;
    for (int pass = 0; pass < 4; ++pass) {
        int shift = 24 - 8 * pass;
        hist[tid] = 0;
        __syncthreads();
        for (int fi = tid; fi < FLAT; fi += 256) {
            unsigned k = flip32(__float_as_uint(sp[fi]));
            if ((k & mask) == prefix) atomicAdd(&hist[(k >> shift) & 255u], 1u);
        }
        __syncthreads();
        if (tid == 0) {
            unsigned cum = 0; int selbin = 0, trem = t;
            for (int bin2 = 255; bin2 >= 0; --bin2) {
                unsigned c = hist[bin2];
                if (cum + c >= (unsigned)t) { selbin = bin2; trem = t - (int)cum; break; }
                cum += c;
            }
            sh_bin = selbin; sh_trem = trem;
        }
        __syncthreads();
        prefix |= ((unsigned)sh_bin) << shift;
        mask   |= 0xFFu << shift;
        t = sh_trem;
        __syncthreads();
    }
    const unsigned T = prefix;

    if (tid == 0) sh_cnt = 0;
    __syncthreads();
    for (int fi = tid; fi < FLAT; fi += 256) {
        unsigned k = flip32(__float_as_uint(sp[fi]));
        if (k >= T) {
            int pos = atomicAdd(&sh_cnt, 1);
            if (pos < 512)
                cand[pos] = ((unsigned long long)k << 32) | (unsigned)(~(unsigned)fi);
        }
    }
    __syncthreads();
    int total = sh_cnt; if (total > 512) total = 512;
    for (int i = tid; i < 512; i += 256) if (i >= total) cand[i] = 0ULL;
    __syncthreads();

    // bitonic sort 512 descending by (score, then lower flat index)
    for (int k = 2; k <= 512; k <<= 1) {
        for (int j = k >> 1; j > 0; j >>= 1) {
            for (int i = tid; i < 512; i += 256) {
                int ixj = i ^ j;
                if (ixj > i) {
                    bool desc = ((i & k) == 0);
                    unsigned long long a = cand[i], c = cand[ixj];
                    if (desc ? (a < c) : (a > c)) { cand[i] = c; cand[ixj] = a; }
                }
            }
            __syncthreads();
        }
    }

    if (tid < DD) {
        unsigned long long key = cand[tid];
        float s; float4 bb; int label;
        if (tid < total && key != 0ULL) {
            unsigned k32 = (unsigned)(key >> 32);
            unsigned fi  = ~(unsigned)(key & 0xFFFFFFFFu);
            s  = __uint_as_float(unflip32(k32));
            bb = flat_b[(size_t)b * FLAT + fi];
            label = (s > 0.0f) ? (int)(fi / KK) + 1 : 0;
        } else {
            s = -1.0f; bb = make_float4(0.0f, 0.0f, 0.0f, 0.0f); label = 0;
        }
        out[(size_t)(b * DD + tid) * 4 + 0] = bb.x;
        out[(size_t)(b * DD + tid) * 4 + 1] = bb.y;
        out[(size_t)(b * DD + tid) * 4 + 2] = bb.z;
        out[(size_t)(b * DD + tid) * 4 + 3] = bb.w;
        out[(size_t)BB * DD * 4 + b * DD + tid] = s;
        out[(size_t)BB * DD * 4 + BB * DD + b * DD + tid] = (float)label;
    }
}

extern "C" void kernel_launch(void* const* d_in, const int* in_sizes, int n_in,
                              void* d_out, int out_size, void* d_ws, size_t ws_size,
                              hipStream_t stream) {
    const float* logits    = (const float*)d_in[0];   // [B*R, 81]
    const float* box_reg   = (const float*)d_in[1];   // [B*R, 324]
    const float* proposals = (const float*)d_in[2];   // [B*R, 4]
    float* out = (float*)d_out;                       // 6400 boxes + 1600 scores + 1600 labels

    float*  probs_t = (float*)d_ws;                                   // 16*80*4096 f32 = 20,971,520 B
    float*  flat_s  = (float*)((char*)d_ws + 20971520);               // 16*24000 f32  =  1,536,000 B
    float4* flat_b  = (float4*)((char*)d_ws + 20971520 + 1536000);    // 16*24000 f32x4 = 6,144,000 B

    softmax_t_kernel<<<(BB * RR) / 64, 256, 0, stream>>>(logits, probs_t);
    percls_kernel<<<BB * NC, 256, 0, stream>>>(probs_t, box_reg, proposals, flat_s, flat_b);
    topd_kernel<<<BB, 256, 0, stream>>>(flat_s, flat_b, out);
}